// Round 11
// baseline (195.364 us; speedup 1.0000x reference)
//
#include <hip/hip_runtime.h>
#include <hip/hip_bf16.h>

#define NN 10240
#define LL 80
#define BB 128

typedef _Float16 half8 __attribute__((ext_vector_type(8)));
typedef _Float16 half2v __attribute__((ext_vector_type(2)));
typedef float f32x4 __attribute__((ext_vector_type(4)));

#define GLD16(gptr, lptr)                                                        \
  __builtin_amdgcn_global_load_lds(                                              \
      (const __attribute__((address_space(1))) void*)(gptr),                     \
      (__attribute__((address_space(3))) void*)(lptr), 16, 0, 0)

__device__ __forceinline__ float dot2f(half2v a, half2v b, float c) {
#if __has_builtin(__builtin_amdgcn_fdot2)
  return __builtin_amdgcn_fdot2(a, b, c, false);
#else
  return c + (float)a.x * (float)b.x + (float)a.y * (float)b.y;
#endif
}
__device__ __forceinline__ half2v u2h(unsigned int u) { half2v r; __builtin_memcpy(&r, &u, 4); return r; }
__device__ __forceinline__ unsigned int h2u(half2v h) { unsigned int u; __builtin_memcpy(&u, &h, 4); return u; }
__device__ __forceinline__ unsigned int dupf16(float v) {
  _Float16 hv = (_Float16)v;
  unsigned short u; __builtin_memcpy(&u, &hv, 2);
  return (unsigned int)u * 0x10001u;
}
// swizzled row offset (f16 units): stride-8 rows land 265 dw apart -> bank step 9 (coprime 32)
__device__ __forceinline__ int roff(int r) { return r * 66 + 2 * (r >> 3); }

// ================= prep_all: gate_scale + 4 weight transposes + bias/att pack ================
__global__ __launch_bounds__(256) void prep_all(
    const float* __restrict__ x, const float* __restrict__ rel,
    const float* __restrict__ w1, const float* __restrict__ b1,
    const float* __restrict__ w2, const float* __restrict__ b2,
    const float* __restrict__ Wl1, const float* __restrict__ Wr1,
    const float* __restrict__ Wl2, const float* __restrict__ Wr2,
    const float* __restrict__ bl1, const float* __restrict__ br1,
    const float* __restrict__ att1,
    _Float16* __restrict__ h0, _Float16* __restrict__ Wt1,
    _Float16* __restrict__ Wt2cat,
    float* __restrict__ biasc, _Float16* __restrict__ att_h) {
  __shared__ float tile[32][33];
  int bid = blockIdx.x;
  int tid = threadIdx.x;
  if (bid < NN) {
    int n = bid;
    __shared__ float s_w;
    if (tid < 64) {
      float r0 = rel[n * 3 + 0], r1 = rel[n * 3 + 1], r2 = rel[n * 3 + 2];
      float v = r0 * w1[tid] + r1 * w1[64 + tid] + r2 * w1[128 + tid] + b1[tid];
      v = v > 0.f ? v : 0.f;
      v *= w2[tid];
      for (int d = 32; d; d >>= 1) v += __shfl_down(v, d, 64);
      if (tid == 0) s_w = 1.f / (1.f + __expf(-(v + b2[0])));
    }
    __syncthreads();
    float w = s_w;
    const float* xr = x + (size_t)n * 768;
    _Float16* hr = h0 + (size_t)n * 768;
    for (int c = tid; c < 768; c += 256) hr[c] = (_Float16)(xr[c] * w);
    return;
  }
  int r = bid - NN;
  const float* W;
  _Float16* Wt;
  int K, Nc, bx, by;
  if (r < 384)      { W = Wl1; Wt = Wt1;                          K = 768; Nc = 512; bx = r % 16;       by = r / 16; }
  else if (r < 768) { W = Wr1; Wt = Wt1 + (size_t)512 * 768;      K = 768; Nc = 512; bx = (r-384) % 16; by = (r-384) / 16; }
  else if (r < 896) { W = Wl2; Wt = Wt2cat;                       K = 512; Nc = 256; bx = (r-768) % 8;  by = (r-768) / 8; }
  else if (r < 1024){ W = Wr2; Wt = Wt2cat + (size_t)256 * 512;   K = 512; Nc = 256; bx = (r-896) % 8;  by = (r-896) / 8; }
  else {
    for (int i = tid; i < 1024; i += 256) biasc[i] = (i < 512) ? bl1[i] : br1[i - 512];
    for (int i = tid; i < 512; i += 256) att_h[i] = (_Float16)att1[i];
    return;
  }
  int n0 = bx * 32, k0 = by * 32;
  int c = tid & 31, rr = tid >> 5;
#pragma unroll
  for (int p = 0; p < 4; ++p) {
    int rw = p * 8 + rr;
    tile[rw][c] = W[(size_t)(k0 + rw) * Nc + n0 + c];
  }
  __syncthreads();
#pragma unroll
  for (int p = 0; p < 4; ++p) {
    int rw = p * 8 + rr;
    Wt[(size_t)(n0 + rw) * K + k0 + c] = (_Float16)tile[c][rw];
  }
}

// ================= fused gemm1 + GATv2 layer-1, K-parity split + swizzled LDS =================
// block = (head, dialogue): h = bx>>7, b = bx&127 (XCD-friendly).
// GEMM: BK=64 (2 subs); waves 0-3 accumulate sub0, waves 4-7 sub1; each wave 2 N-strips.
// Cross-group reduction via packed-f16 LDS buf (pitch 41 dw). Then logits/softmax/agg (roff).
__global__ __launch_bounds__(512, 8) void gemm1gat1(
    const _Float16* __restrict__ h0, const _Float16* __restrict__ Wt1,
    const float* __restrict__ biasc, const _Float16* __restrict__ att_h,
    const float* __restrict__ bias1, _Float16* __restrict__ h1) {
  __shared__ __align__(16) char smem[37056];
  // gemm phase: As[2][80][32] = 10240 B @0, Bs[2][128][32] = 16384 B @10240 (end 26624)
  _Float16* As = (_Float16*)smem;
  _Float16* Bs = (_Float16*)(smem + 10240);
  unsigned int* red = (unsigned int*)smem;                 // 128*41*4 = 20992 (reduction)
  // gat phase (overlays):
  _Float16* s_xl = (_Float16*)smem;                        // 10624 (swizzled rows)
  _Float16* s_xr = (_Float16*)(smem + 10624);              // 10624
  float* s_logit = (float*)(smem + 21248);                 // 5184
  unsigned int* s_al = (unsigned int*)(smem + 26432);      // 5184
  short* s_src   = (short*)(smem + 31616);                 // 2592
  short* s_cnt   = (short*)(smem + 34208);                 // 160
  float* s_hub   = (float*)(smem + 34368);                 // 320
  unsigned int* s_hub16 = (unsigned int*)(smem + 34688);   // 320
  unsigned int* s_hp = (unsigned int*)(smem + 35008);      // 2048

  int bx = blockIdx.x;
  int h = bx >> 7, b = bx & 127;
  int base = b * LL;
  int tid = threadIdx.x;
  int wave = tid >> 6, lane = tid & 63;
  int lr = lane & 15, lk = lane >> 4;
  int g = wave >> 2, np = wave & 3;

  // ---- staging pointers ----
  const _Float16* aP = h0;
  if (wave < 5) {
    // A chunk = tid (row = tid>>2 in [0,80), seg = tid&3); LDS off = tid*8 (per sub)
    aP = h0 + (size_t)(base + (tid >> 2)) * 768 + (tid & 3) * 8;
  }
  int brow = tid >> 2;  // 0..127
  int wrow = (brow < 64) ? (h * 64 + brow) : (512 + h * 64 + (brow - 64));
  const _Float16* bP = Wt1 + (size_t)wrow * 768 + (tid & 3) * 8;

  f32x4 acc[5][2] = {};
  const _Float16* bbase = Bs + g * 4096 + (np * 32 + lr) * 32 + lk * 8;
  const _Float16* abase = As + g * 2560 + lr * 32 + lk * 8;
  for (int it = 0; it < 12; ++it) {
    int k0 = it * 64;
    if (wave < 5) {
      GLD16(aP + k0,      As + tid * 8);
      GLD16(aP + k0 + 32, As + 2560 + tid * 8);
    }
    GLD16(bP + k0,      Bs + tid * 8);
    GLD16(bP + k0 + 32, Bs + 4096 + tid * 8);
    __syncthreads();
    half8 bf0 = *(const half8*)(bbase);
    half8 bf1 = *(const half8*)(bbase + 512);
#pragma unroll
    for (int m = 0; m < 5; ++m) {
      half8 af = *(const half8*)(abase + m * 512);
      acc[m][0] = __builtin_amdgcn_mfma_f32_16x16x32_f16(af, bf0, acc[m][0], 0, 0, 0);
      acc[m][1] = __builtin_amdgcn_mfma_f32_16x16x32_f16(af, bf1, acc[m][1], 0, 0, 0);
    }
    __syncthreads();
  }
  // ---- cross-group reduction: group1 -> LDS (packed f16), group0 adds ----
  if (wave >= 4) {
#pragma unroll
    for (int m = 0; m < 5; ++m)
#pragma unroll
      for (int s = 0; s < 2; ++s) {
        int col = np * 32 + s * 16 + lr;
        int rbase = col * 41 + 8 * m + 2 * lk;
#pragma unroll
        for (int rp = 0; rp < 2; ++rp) {
          half2v pv = {(_Float16)acc[m][s][2 * rp], (_Float16)acc[m][s][2 * rp + 1]};
          red[rbase + rp] = h2u(pv);
        }
      }
  }
  __syncthreads();
  if (wave < 4) {
#pragma unroll
    for (int m = 0; m < 5; ++m)
#pragma unroll
      for (int s = 0; s < 2; ++s) {
        int col = np * 32 + s * 16 + lr;
        int rbase = col * 41 + 8 * m + 2 * lk;
#pragma unroll
        for (int rp = 0; rp < 2; ++rp) {
          half2v pv = u2h(red[rbase + rp]);
          acc[m][s][2 * rp] += (float)pv.x;
          acc[m][s][2 * rp + 1] += (float)pv.y;
        }
      }
  }
  __syncthreads();  // red dead; s_xl/s_xr region safe to write

  // ---- epilogue (group0): xl/xr (+bias) into swizzled LDS tiles; adjacency build ----
  if (wave < 4) {
#pragma unroll
    for (int s = 0; s < 2; ++s) {
      int col = np * 32 + s * 16 + lr;
      bool isxl = col < 64;
      int cc = isxl ? col : col - 64;
      float bb = biasc[(isxl ? 0 : 512) + h * 64 + cc];
      _Float16* dst = isxl ? s_xl : s_xr;
#pragma unroll
      for (int m = 0; m < 5; ++m)
#pragma unroll
        for (int rg = 0; rg < 4; ++rg) {
          int row = m * 16 + lk * 4 + rg;
          dst[roff(row) + cc] = (_Float16)(acc[m][s][rg] + bb);
        }
    }
  }
  if (tid < 79) {
    int d = tid;
    int list[16];
    int c = 0;
    list[c++] = d;
    if (d > 0) list[c++] = d - 1;
    if (d + 1 < 79) list[c++] = d + 1;
    list[c++] = 79;
    for (int j = d & 7; j < 80; j += 8)
      if (j != d && j != 79) list[c++] = j;
    s_cnt[d] = (short)c;
    for (int i = c; i < 16; ++i) list[i] = -1;
#pragma unroll
    for (int i = 0; i < 16; ++i) s_src[i * 81 + d] = (short)list[i];
  }
  __syncthreads();

  // ---- edge logits: lane = slot (1264 table slots + 80 hub) ----
  const unsigned int* pat = (const unsigned int*)(att_h + h * 64);
  const half2v c02 = {(_Float16)0.2f, (_Float16)0.2f};
  for (int s = tid; s < 1344; s += 512) {
    int d, src;
    bool ishub = s >= 1264;
    if (!ishub) { d = s >> 4; src = s_src[(s & 15) * 81 + d]; }
    else { d = 79; src = s - 1264; }
    int ssrc = src < 0 ? 0 : src;
    const unsigned int* pa = (const unsigned int*)(s_xl + roff(ssrc));
    const unsigned int* pb = (const unsigned int*)(s_xr + roff(d));
    float acc2 = 0.f;
#pragma unroll
    for (int q = 0; q < 16; ++q) {
      unsigned int a0 = pa[2 * q], a1 = pa[2 * q + 1];
      unsigned int b0 = pb[2 * q], b1 = pb[2 * q + 1];
      half2v at0 = u2h(__builtin_amdgcn_readfirstlane(pat[2 * q]));
      half2v at1 = u2h(__builtin_amdgcn_readfirstlane(pat[2 * q + 1]));
      half2v e0 = u2h(a0) + u2h(b0);
      half2v e1 = u2h(a1) + u2h(b1);
      half2v l0 = __builtin_elementwise_max(e0, e0 * c02);
      half2v l1 = __builtin_elementwise_max(e1, e1 * c02);
      acc2 = dot2f(l0, at0, acc2);
      acc2 = dot2f(l1, at1, acc2);
    }
    if (!ishub) s_logit[(s & 15) * 81 + d] = (src < 0) ? -3e38f : acc2;
    else s_hub[src] = acc2;
  }
  __syncthreads();

  // ---- segment softmax -> alpha (dup-packed f16) ----
  if (tid < 79) {
    int d = tid;
    float m = -3e38f, v[16];
#pragma unroll
    for (int i = 0; i < 16; ++i) { v[i] = s_logit[i * 81 + d]; m = fmaxf(m, v[i]); }
    float sum = 0.f;
#pragma unroll
    for (int i = 0; i < 16; ++i) { v[i] = __expf(v[i] - m); sum += v[i]; }
    float inv = 1.f / sum;
#pragma unroll
    for (int i = 0; i < 16; ++i) s_al[i * 81 + d] = dupf16(v[i] * inv);
  } else if (tid >= 448) {
    int l = tid - 448;
    float v0 = s_hub[l];
    float v1 = (l < 16) ? s_hub[64 + l] : -3e38f;
    float m = fmaxf(v0, v1);
    for (int d = 32; d; d >>= 1) m = fmaxf(m, __shfl_xor(m, d, 64));
    float e0 = __expf(v0 - m);
    float e1 = (l < 16) ? __expf(v1 - m) : 0.f;
    float sum = e0 + e1;
    for (int d = 32; d; d >>= 1) sum += __shfl_xor(sum, d, 64);
    float inv = 1.f / sum;
    s_hub16[l] = dupf16(e0 * inv);
    if (l < 16) s_hub16[64 + l] = dupf16(e1 * inv);
  }
  __syncthreads();

  // ---- aggregation: 16-lane group per dst, lane = 4 channels, pk f16 ----
  int qw = tid >> 4, l = tid & 15;
  int c0 = l * 4;
#pragma unroll
  for (int k = 0; k < 3; ++k) {
    int d = qw + 32 * k;
    if (d >= 79) continue;
    int cnt = s_cnt[d];
    half2v a0 = {(_Float16)0.f, (_Float16)0.f};
    half2v a1 = a0;
    for (int i = 0; i < cnt; ++i) {
      int src = s_src[i * 81 + d];
      half2v al = u2h(s_al[i * 81 + d]);
      const unsigned int* px = (const unsigned int*)(s_xl + roff(src) + c0);
      a0 += al * u2h(px[0]);
      a1 += al * u2h(px[1]);
    }
    float v0 = (float)a0.x + bias1[h * 64 + c0];
    float v1 = (float)a0.y + bias1[h * 64 + c0 + 1];
    float v2 = (float)a1.x + bias1[h * 64 + c0 + 2];
    float v3 = (float)a1.y + bias1[h * 64 + c0 + 3];
    v0 = v0 > 0.f ? v0 : __expf(v0) - 1.f;
    v1 = v1 > 0.f ? v1 : __expf(v1) - 1.f;
    v2 = v2 > 0.f ? v2 : __expf(v2) - 1.f;
    v3 = v3 > 0.f ? v3 : __expf(v3) - 1.f;
    half2v o0 = {(_Float16)v0, (_Float16)v1};
    half2v o1 = {(_Float16)v2, (_Float16)v3};
    uint2 ov = {h2u(o0), h2u(o1)};
    *(uint2*)&h1[(size_t)(base + d) * 512 + h * 64 + c0] = ov;
  }
  // hub partials: groups 16..31, 5 srcs each
  if (qw >= 16) {
    int gg = qw - 16;
    half2v a0 = {(_Float16)0.f, (_Float16)0.f};
    half2v a1 = a0;
#pragma unroll
    for (int s5 = 0; s5 < 5; ++s5) {
      int src = gg * 5 + s5;
      half2v al = u2h(s_hub16[src]);
      const unsigned int* px = (const unsigned int*)(s_xl + roff(src) + c0);
      a0 += al * u2h(px[0]);
      a1 += al * u2h(px[1]);
    }
    s_hp[gg * 32 + 2 * l] = h2u(a0);
    s_hp[gg * 32 + 2 * l + 1] = h2u(a1);
  }
  __syncthreads();
  if (tid < 32) {
    float f0 = 0.f, f1 = 0.f;
#pragma unroll
    for (int gg = 0; gg < 16; ++gg) {
      half2v v = u2h(s_hp[gg * 32 + tid]);
      f0 += (float)v.x;
      f1 += (float)v.y;
    }
    int c = tid * 2;
    float v0 = f0 + bias1[h * 64 + c];
    float v1 = f1 + bias1[h * 64 + c + 1];
    v0 = v0 > 0.f ? v0 : __expf(v0) - 1.f;
    v1 = v1 > 0.f ? v1 : __expf(v1) - 1.f;
    half2v o = {(_Float16)v0, (_Float16)v1};
    *(unsigned int*)&h1[(size_t)(base + 79) * 512 + h * 64 + c] = h2u(o);
  }
}

// ================= fused gemm2 + gat2 + LN: one dialogue per block (512 threads) ==============
#define PX 266
__global__ __launch_bounds__(512) void gemm2gat2(
    const _Float16* __restrict__ h1, const _Float16* __restrict__ Bt,
    const float* __restrict__ bl2, const float* __restrict__ br2,
    const float* __restrict__ att2, const float* __restrict__ bias2,
    const float* __restrict__ ln_g, const float* __restrict__ ln_b,
    float* __restrict__ out) {
  __shared__ __align__(16) char smem[80 * PX * 2];
  __shared__ _Float16 s_att[256];
  __shared__ _Float16 s_xr[256];
  __shared__ float s_red[80];
  __shared__ float s_sum[4], s_sq[4];
  _Float16* As = (_Float16*)smem;
  _Float16* Bs = (_Float16*)(smem + 5120);
  _Float16* s_x = (_Float16*)smem;

  int b = blockIdx.x;
  int tid = threadIdx.x;
  int wave = tid >> 6, lane = tid & 63;
  int lr = lane & 15, lk = lane >> 4;

  if (tid < 256) s_att[tid] = (_Float16)att2[tid];

  int achunk = wave * 64 + lane;
  const _Float16* aP = h1 + (size_t)(b * 80 + (achunk >> 2)) * 512 + (achunk & 3) * 8;
  const _Float16* bP[4];
#pragma unroll
  for (int j = 0; j < 4; ++j) {
    int c = wave * 256 + j * 64 + lane;
    bP[j] = Bt + (size_t)(c >> 2) * 512 + (c & 3) * 8;
  }
  f32x4 acc[5][4] = {};
  for (int k0 = 0; k0 < 512; k0 += 32) {
    if (wave < 5) GLD16(aP + k0, As + wave * 512);
#pragma unroll
    for (int j = 0; j < 4; ++j)
      GLD16(bP[j] + k0, Bs + (wave * 256 + j * 64) * 8);
    __syncthreads();
    half8 af[5], bfv;
#pragma unroll
    for (int i = 0; i < 5; ++i)
      af[i] = *(const half8*)(As + (i * 16 + lr) * 32 + lk * 8);
#pragma unroll
    for (int j = 0; j < 4; ++j) {
      bfv = *(const half8*)(Bs + (wave * 64 + j * 16 + lr) * 32 + lk * 8);
#pragma unroll
      for (int i = 0; i < 5; ++i)
        acc[i][j] = __builtin_amdgcn_mfma_f32_16x16x32_f16(af[i], bfv, acc[i][j], 0, 0, 0);
    }
    __syncthreads();
  }
  if (wave < 4) {
#pragma unroll
    for (int i = 0; i < 5; ++i)
#pragma unroll
      for (int j = 0; j < 4; ++j)
#pragma unroll
        for (int rg = 0; rg < 4; ++rg) {
          int row = i * 16 + lk * 4 + rg;
          int col = wave * 64 + j * 16 + lr;
          s_x[row * PX + col] = (_Float16)(acc[i][j][rg] + bl2[col]);
        }
  } else if (lk == 3) {
#pragma unroll
    for (int j = 0; j < 4; ++j) {
      int colx = (wave - 4) * 64 + j * 16 + lr;
      s_xr[colx] = (_Float16)(acc[4][j][3] + br2[colx]);
    }
  }
  __syncthreads();
  if (tid < 160) {
    int r = tid >> 1, hf = tid & 1;
    const half2v* xa = (const half2v*)(s_x + r * PX + hf * 128);
    const half2v* xr = (const half2v*)(s_xr + hf * 128);
    const half2v* at = (const half2v*)(s_att + hf * 128);
    float lg = 0.f;
    const half2v c02 = {(_Float16)0.2f, (_Float16)0.2f};
#pragma unroll
    for (int q = 0; q < 64; ++q) {
      half2v e = xa[q] + xr[q];
      half2v l = __builtin_elementwise_max(e, e * c02);
      lg = dot2f(l, at[q], lg);
    }
    lg += __shfl_xor(lg, 1, 64);
    if (hf == 0) s_red[r] = lg;
  }
  __syncthreads();
  if (wave == 7) {
    float v0 = s_red[lane];
    float v1 = (lane < 16) ? s_red[64 + lane] : -3e38f;
    float m = fmaxf(v0, v1);
    for (int d = 32; d; d >>= 1) m = fmaxf(m, __shfl_xor(m, d, 64));
    float e0 = __expf(v0 - m);
    float e1 = (lane < 16) ? __expf(v1 - m) : 0.f;
    float sum = e0 + e1;
    for (int d = 32; d; d >>= 1) sum += __shfl_xor(sum, d, 64);
    float inv = 1.f / sum;
    s_red[lane] = e0 * inv;
    if (lane < 16) s_red[64 + lane] = e1 * inv;
  }
  __syncthreads();
  float v = 0.f;
  if (tid < 256) {
    float a = 0.f;
#pragma unroll
    for (int r = 0; r < 80; ++r) a += s_red[r] * (float)s_x[r * PX + tid];
    v = a + bias2[tid];
    float p = v;
    for (int d = 32; d; d >>= 1) p += __shfl_down(p, d, 64);
    if (lane == 0) s_sum[wave] = p;
    float q = v * v;
    for (int d = 32; d; d >>= 1) q += __shfl_down(q, d, 64);
    if (lane == 0) s_sq[wave] = q;
  }
  __syncthreads();
  if (tid < 256) {
    float mu = (s_sum[0] + s_sum[1] + s_sum[2] + s_sum[3]) * (1.f / 256.f);
    float ex2 = (s_sq[0] + s_sq[1] + s_sq[2] + s_sq[3]) * (1.f / 256.f);
    float var = ex2 - mu * mu;
    float r = rsqrtf(var + 1e-5f);
    out[b * 256 + tid] = (v - mu) * r * ln_g[tid] + ln_b[tid];
  }
}

extern "C" void kernel_launch(void* const* d_in, const int* in_sizes, int n_in,
                              void* d_out, int out_size, void* d_ws, size_t ws_size,
                              hipStream_t stream) {
  const float* x      = (const float*)d_in[0];
  const float* rel    = (const float*)d_in[1];
  const float* w1     = (const float*)d_in[2];
  const float* b1     = (const float*)d_in[3];
  const float* w2     = (const float*)d_in[4];
  const float* b2     = (const float*)d_in[5];
  const float* Wl1    = (const float*)d_in[6];
  const float* bl1    = (const float*)d_in[7];
  const float* Wr1    = (const float*)d_in[8];
  const float* br1    = (const float*)d_in[9];
  const float* att1   = (const float*)d_in[10];
  const float* bias1  = (const float*)d_in[11];
  const float* Wl2    = (const float*)d_in[12];
  const float* bl2    = (const float*)d_in[13];
  const float* Wr2    = (const float*)d_in[14];
  const float* br2    = (const float*)d_in[15];
  const float* att2   = (const float*)d_in[16];
  const float* bias2  = (const float*)d_in[17];
  const float* ln_g   = (const float*)d_in[18];
  const float* ln_b   = (const float*)d_in[19];
  float* out = (float*)d_out;

  char* p = (char*)d_ws;
  _Float16* h0     = (_Float16*)p; p += (size_t)NN * 768 * 2;
  _Float16* h1     = (_Float16*)p; p += (size_t)NN * 512 * 2;
  _Float16* Wt1    = (_Float16*)p; p += (size_t)1024 * 768 * 2;
  _Float16* Wt2cat = (_Float16*)p; p += (size_t)512 * 512 * 2;
  _Float16* att_h  = (_Float16*)p; p += 1024;
  float* biasc     = (float*)p; p += 1024 * 4;

  prep_all<<<NN + 1025, 256, 0, stream>>>(x, rel, w1, b1, w2, b2, Wl1, Wr1, Wl2, Wr2,
                                          bl1, br1, att1, h0, Wt1, Wt2cat, biasc, att_h);

  gemm1gat1<<<1024, 512, 0, stream>>>(h0, Wt1, biasc, att_h, bias1, h1);

  gemm2gat2<<<BB, 512, 0, stream>>>(h1, Wt2cat, bl2, br2, att2, bias2, ln_g, ln_b, out);
}

// Round 12
// 185.684 us; speedup vs baseline: 1.0521x; 1.0521x over previous
//
#include <hip/hip_runtime.h>
#include <hip/hip_bf16.h>

#define NN 10240
#define LL 80
#define BB 128

typedef _Float16 half8 __attribute__((ext_vector_type(8)));
typedef _Float16 half2v __attribute__((ext_vector_type(2)));
typedef float f32x4 __attribute__((ext_vector_type(4)));

#define GLD16(gptr, lptr)                                                        \
  __builtin_amdgcn_global_load_lds(                                              \
      (const __attribute__((address_space(1))) void*)(gptr),                     \
      (__attribute__((address_space(3))) void*)(lptr), 16, 0, 0)

__device__ __forceinline__ float dot2f(half2v a, half2v b, float c) {
#if __has_builtin(__builtin_amdgcn_fdot2)
  return __builtin_amdgcn_fdot2(a, b, c, false);
#else
  return c + (float)a.x * (float)b.x + (float)a.y * (float)b.y;
#endif
}
__device__ __forceinline__ half2v u2h(unsigned int u) { half2v r; __builtin_memcpy(&r, &u, 4); return r; }
__device__ __forceinline__ unsigned int h2u(half2v h) { unsigned int u; __builtin_memcpy(&u, &h, 4); return u; }
__device__ __forceinline__ unsigned int dupf16(float v) {
  _Float16 hv = (_Float16)v;
  unsigned short u; __builtin_memcpy(&u, &hv, 2);
  return (unsigned int)u * 0x10001u;
}
// swizzled row offset (f16 units): stride-8 peer rows step 266 dw = 10 mod 32 (16-bank cycle)
__device__ __forceinline__ int roff(int r) { return r * 66 + 4 * (r >> 3); }

// ================= prep_all: gate_scale + 4 weight transposes + bias/att pack ================
__global__ __launch_bounds__(256) void prep_all(
    const float* __restrict__ x, const float* __restrict__ rel,
    const float* __restrict__ w1, const float* __restrict__ b1,
    const float* __restrict__ w2, const float* __restrict__ b2,
    const float* __restrict__ Wl1, const float* __restrict__ Wr1,
    const float* __restrict__ Wl2, const float* __restrict__ Wr2,
    const float* __restrict__ bl1, const float* __restrict__ br1,
    const float* __restrict__ att1,
    _Float16* __restrict__ h0, _Float16* __restrict__ Wt1,
    _Float16* __restrict__ Wt2cat,
    float* __restrict__ biasc, _Float16* __restrict__ att_h) {
  __shared__ float tile[32][33];
  int bid = blockIdx.x;
  int tid = threadIdx.x;
  if (bid < NN) {
    int n = bid;
    __shared__ float s_w;
    if (tid < 64) {
      float r0 = rel[n * 3 + 0], r1 = rel[n * 3 + 1], r2 = rel[n * 3 + 2];
      float v = r0 * w1[tid] + r1 * w1[64 + tid] + r2 * w1[128 + tid] + b1[tid];
      v = v > 0.f ? v : 0.f;
      v *= w2[tid];
      for (int d = 32; d; d >>= 1) v += __shfl_down(v, d, 64);
      if (tid == 0) s_w = 1.f / (1.f + __expf(-(v + b2[0])));
    }
    __syncthreads();
    float w = s_w;
    const float* xr = x + (size_t)n * 768;
    _Float16* hr = h0 + (size_t)n * 768;
    for (int c = tid; c < 768; c += 256) hr[c] = (_Float16)(xr[c] * w);
    return;
  }
  int r = bid - NN;
  const float* W;
  _Float16* Wt;
  int K, Nc, bx, by;
  if (r < 384)      { W = Wl1; Wt = Wt1;                          K = 768; Nc = 512; bx = r % 16;       by = r / 16; }
  else if (r < 768) { W = Wr1; Wt = Wt1 + (size_t)512 * 768;      K = 768; Nc = 512; bx = (r-384) % 16; by = (r-384) / 16; }
  else if (r < 896) { W = Wl2; Wt = Wt2cat;                       K = 512; Nc = 256; bx = (r-768) % 8;  by = (r-768) / 8; }
  else if (r < 1024){ W = Wr2; Wt = Wt2cat + (size_t)256 * 512;   K = 512; Nc = 256; bx = (r-896) % 8;  by = (r-896) / 8; }
  else {
    for (int i = tid; i < 1024; i += 256) biasc[i] = (i < 512) ? bl1[i] : br1[i - 512];
    for (int i = tid; i < 512; i += 256) att_h[i] = (_Float16)att1[i];
    return;
  }
  int n0 = bx * 32, k0 = by * 32;
  int c = tid & 31, rr = tid >> 5;
#pragma unroll
  for (int p = 0; p < 4; ++p) {
    int rw = p * 8 + rr;
    tile[rw][c] = W[(size_t)(k0 + rw) * Nc + n0 + c];
  }
  __syncthreads();
#pragma unroll
  for (int p = 0; p < 4; ++p) {
    int rw = p * 8 + rr;
    Wt[(size_t)(n0 + rw) * K + k0 + c] = (_Float16)tile[c][rw];
  }
}

// ================= fused gemm1 + GATv2 layer-1 (R10 structure + fixed swizzle) ================
// block = (head, dialogue): h = bx>>7, b = bx&127 (XCD-friendly).
// Phase 1 (MFMA, BK=96): [80,768] @ Wt1-slice[768,128] -> xl|xr in swizzled LDS tiles.
// Phase 2 (VALU): edge logits -> segment softmax -> f16 aggregation -> ELU -> h1.
__global__ __launch_bounds__(512, 8) void gemm1gat1(
    const _Float16* __restrict__ h0, const _Float16* __restrict__ Wt1,
    const float* __restrict__ biasc, const _Float16* __restrict__ att_h,
    const float* __restrict__ bias1, _Float16* __restrict__ h1) {
  __shared__ __align__(16) char smem[39936];
  // gemm phase: As[3][80][32] = 15360 B, Bs[3][128][32] = 24576 B
  _Float16* As = (_Float16*)smem;
  _Float16* Bs = (_Float16*)(smem + 15360);
  // gat phase (overlays staging; roff max = 79*66+36 = 5250 f16 + 66 -> 10640 B/tile):
  _Float16* s_xl = (_Float16*)smem;                        // @0     10640
  _Float16* s_xr = (_Float16*)(smem + 10640);              // @10640 10640
  float* s_logit = (float*)(smem + 21280);                 // 5184
  unsigned int* s_al = (unsigned int*)(smem + 26464);      // 5184
  short* s_src   = (short*)(smem + 31648);                 // 2592
  short* s_cnt   = (short*)(smem + 34240);                 // 160
  float* s_hub   = (float*)(smem + 34400);                 // 320
  unsigned int* s_hub16 = (unsigned int*)(smem + 34720);   // 320
  unsigned int* s_hp = (unsigned int*)(smem + 35040);      // 2048 -> end 37088

  int bx = blockIdx.x;
  int h = bx >> 7, b = bx & 127;
  int base = b * LL;
  int tid = threadIdx.x;
  int wave = tid >> 6, lane = tid & 63;
  int lr = lane & 15, lk = lane >> 4;

  // ---- gemm staging pointers ----
  const _Float16* aP = h0;  // valid only for wave<5
  if (wave < 5) {
    int c = wave * 64 + lane;  // A chunk 0..319: row = c>>2, seg = c&3
    aP = h0 + (size_t)(base + (c >> 2)) * 768 + (c & 3) * 8;
  }
  int cB = wave * 64 + lane;   // B chunk 0..511: row = cB>>2 in [0,128)
  int brow = cB >> 2;
  int wrow = (brow < 64) ? (h * 64 + brow) : (512 + h * 64 + (brow - 64));
  const _Float16* bP = Wt1 + (size_t)wrow * 768 + (cB & 3) * 8;

  f32x4 acc[5] = {};
  for (int it = 0; it < 8; ++it) {
    int k0 = it * 96;
    if (wave < 5) {
      GLD16(aP + k0,      As + wave * 512);
      GLD16(aP + k0 + 32, As + 2560 + wave * 512);
      GLD16(aP + k0 + 64, As + 5120 + wave * 512);
    }
    GLD16(bP + k0,      Bs + wave * 512);
    GLD16(bP + k0 + 32, Bs + 4096 + wave * 512);
    GLD16(bP + k0 + 64, Bs + 8192 + wave * 512);
    __syncthreads();
#pragma unroll
    for (int s3 = 0; s3 < 3; ++s3) {
      half8 bf = *(const half8*)(Bs + s3 * 4096 + (wave * 16 + lr) * 32 + lk * 8);
#pragma unroll
      for (int m = 0; m < 5; ++m) {
        half8 af = *(const half8*)(As + s3 * 2560 + (m * 16 + lr) * 32 + lk * 8);
        acc[m] = __builtin_amdgcn_mfma_f32_16x16x32_f16(af, bf, acc[m], 0, 0, 0);
      }
    }
    __syncthreads();
  }
  // ---- epilogue: xl/xr (+bias) into swizzled LDS tiles; adjacency build ----
  {
    int c = wave * 16 + lr;          // 0..127
    bool isxl = c < 64;
    int cc = isxl ? c : c - 64;
    float bb = biasc[(isxl ? 0 : 512) + h * 64 + cc];
    _Float16* dst = isxl ? s_xl : s_xr;
#pragma unroll
    for (int m = 0; m < 5; ++m)
#pragma unroll
      for (int rg = 0; rg < 4; ++rg) {
        int row = m * 16 + lk * 4 + rg;
        dst[roff(row) + cc] = (_Float16)(acc[m][rg] + bb);
      }
  }
  if (tid < 79) {
    int d = tid;
    int list[16];
    int c = 0;
    list[c++] = d;
    if (d > 0) list[c++] = d - 1;
    if (d + 1 < 79) list[c++] = d + 1;
    list[c++] = 79;
    for (int j = d & 7; j < 80; j += 8)
      if (j != d && j != 79) list[c++] = j;
    s_cnt[d] = (short)c;
    for (int i = c; i < 16; ++i) list[i] = -1;
#pragma unroll
    for (int i = 0; i < 16; ++i) s_src[i * 81 + d] = (short)list[i];
  }
  __syncthreads();

  // ---- edge logits: lane = slot (1264 table slots + 80 hub) ----
  const unsigned int* pat = (const unsigned int*)(att_h + h * 64);
  const half2v c02 = {(_Float16)0.2f, (_Float16)0.2f};
  for (int s = tid; s < 1344; s += 512) {
    int d, src;
    bool ishub = s >= 1264;
    if (!ishub) { d = s >> 4; src = s_src[(s & 15) * 81 + d]; }
    else { d = 79; src = s - 1264; }
    int ssrc = src < 0 ? 0 : src;
    const unsigned int* pa = (const unsigned int*)(s_xl + roff(ssrc));
    const unsigned int* pb = (const unsigned int*)(s_xr + roff(d));
    float acc2 = 0.f;
#pragma unroll
    for (int q = 0; q < 16; ++q) {
      unsigned int a0 = pa[2 * q], a1 = pa[2 * q + 1];
      unsigned int b0 = pb[2 * q], b1 = pb[2 * q + 1];
      half2v at0 = u2h(__builtin_amdgcn_readfirstlane(pat[2 * q]));
      half2v at1 = u2h(__builtin_amdgcn_readfirstlane(pat[2 * q + 1]));
      half2v e0 = u2h(a0) + u2h(b0);
      half2v e1 = u2h(a1) + u2h(b1);
      half2v l0 = __builtin_elementwise_max(e0, e0 * c02);
      half2v l1 = __builtin_elementwise_max(e1, e1 * c02);
      acc2 = dot2f(l0, at0, acc2);
      acc2 = dot2f(l1, at1, acc2);
    }
    if (!ishub) s_logit[(s & 15) * 81 + d] = (src < 0) ? -3e38f : acc2;
    else s_hub[src] = acc2;
  }
  __syncthreads();

  // ---- segment softmax -> alpha (dup-packed f16) ----
  if (tid < 79) {
    int d = tid;
    float m = -3e38f, v[16];
#pragma unroll
    for (int i = 0; i < 16; ++i) { v[i] = s_logit[i * 81 + d]; m = fmaxf(m, v[i]); }
    float sum = 0.f;
#pragma unroll
    for (int i = 0; i < 16; ++i) { v[i] = __expf(v[i] - m); sum += v[i]; }
    float inv = 1.f / sum;
#pragma unroll
    for (int i = 0; i < 16; ++i) s_al[i * 81 + d] = dupf16(v[i] * inv);
  } else if (tid >= 448) {
    int l = tid - 448;
    float v0 = s_hub[l];
    float v1 = (l < 16) ? s_hub[64 + l] : -3e38f;
    float m = fmaxf(v0, v1);
    for (int d = 32; d; d >>= 1) m = fmaxf(m, __shfl_xor(m, d, 64));
    float e0 = __expf(v0 - m);
    float e1 = (l < 16) ? __expf(v1 - m) : 0.f;
    float sum = e0 + e1;
    for (int d = 32; d; d >>= 1) sum += __shfl_xor(sum, d, 64);
    float inv = 1.f / sum;
    s_hub16[l] = dupf16(e0 * inv);
    if (l < 16) s_hub16[64 + l] = dupf16(e1 * inv);
  }
  __syncthreads();

  // ---- aggregation: 16-lane group per dst, lane = 4 channels, pk f16 ----
  int qw = tid >> 4, l = tid & 15;
  int c0 = l * 4;
#pragma unroll
  for (int k = 0; k < 3; ++k) {
    int d = qw + 32 * k;
    if (d >= 79) continue;
    int cnt = s_cnt[d];
    half2v a0 = {(_Float16)0.f, (_Float16)0.f};
    half2v a1 = a0;
    for (int i = 0; i < cnt; ++i) {
      int src = s_src[i * 81 + d];
      half2v al = u2h(s_al[i * 81 + d]);
      const unsigned int* px = (const unsigned int*)(s_xl + roff(src) + c0);
      a0 += al * u2h(px[0]);
      a1 += al * u2h(px[1]);
    }
    float v0 = (float)a0.x + bias1[h * 64 + c0];
    float v1 = (float)a0.y + bias1[h * 64 + c0 + 1];
    float v2 = (float)a1.x + bias1[h * 64 + c0 + 2];
    float v3 = (float)a1.y + bias1[h * 64 + c0 + 3];
    v0 = v0 > 0.f ? v0 : __expf(v0) - 1.f;
    v1 = v1 > 0.f ? v1 : __expf(v1) - 1.f;
    v2 = v2 > 0.f ? v2 : __expf(v2) - 1.f;
    v3 = v3 > 0.f ? v3 : __expf(v3) - 1.f;
    half2v o0 = {(_Float16)v0, (_Float16)v1};
    half2v o1 = {(_Float16)v2, (_Float16)v3};
    uint2 ov = {h2u(o0), h2u(o1)};
    *(uint2*)&h1[(size_t)(base + d) * 512 + h * 64 + c0] = ov;
  }
  // hub partials: groups 16..31, 5 srcs each
  if (qw >= 16) {
    int g = qw - 16;
    half2v a0 = {(_Float16)0.f, (_Float16)0.f};
    half2v a1 = a0;
#pragma unroll
    for (int s5 = 0; s5 < 5; ++s5) {
      int src = g * 5 + s5;
      half2v al = u2h(s_hub16[src]);
      const unsigned int* px = (const unsigned int*)(s_xl + roff(src) + c0);
      a0 += al * u2h(px[0]);
      a1 += al * u2h(px[1]);
    }
    s_hp[g * 32 + 2 * l] = h2u(a0);
    s_hp[g * 32 + 2 * l + 1] = h2u(a1);
  }
  __syncthreads();
  if (tid < 32) {
    float f0 = 0.f, f1 = 0.f;
#pragma unroll
    for (int g = 0; g < 16; ++g) {
      half2v v = u2h(s_hp[g * 32 + tid]);
      f0 += (float)v.x;
      f1 += (float)v.y;
    }
    int c = tid * 2;
    float v0 = f0 + bias1[h * 64 + c];
    float v1 = f1 + bias1[h * 64 + c + 1];
    v0 = v0 > 0.f ? v0 : __expf(v0) - 1.f;
    v1 = v1 > 0.f ? v1 : __expf(v1) - 1.f;
    half2v o = {(_Float16)v0, (_Float16)v1};
    *(unsigned int*)&h1[(size_t)(base + 79) * 512 + h * 64 + c] = h2u(o);
  }
}

// ================= fused gemm2 + gat2 + LN: one dialogue per block (512 threads) ==============
#define PX 266
__global__ __launch_bounds__(512) void gemm2gat2(
    const _Float16* __restrict__ h1, const _Float16* __restrict__ Bt,
    const float* __restrict__ bl2, const float* __restrict__ br2,
    const float* __restrict__ att2, const float* __restrict__ bias2,
    const float* __restrict__ ln_g, const float* __restrict__ ln_b,
    float* __restrict__ out) {
  __shared__ __align__(16) char smem[80 * PX * 2];
  __shared__ _Float16 s_att[256];
  __shared__ _Float16 s_xr[256];
  __shared__ float s_red[80];
  __shared__ float s_sum[4], s_sq[4];
  _Float16* As = (_Float16*)smem;
  _Float16* Bs = (_Float16*)(smem + 5120);
  _Float16* s_x = (_Float16*)smem;

  int b = blockIdx.x;
  int tid = threadIdx.x;
  int wave = tid >> 6, lane = tid & 63;
  int lr = lane & 15, lk = lane >> 4;

  if (tid < 256) s_att[tid] = (_Float16)att2[tid];

  int achunk = wave * 64 + lane;
  const _Float16* aP = h1 + (size_t)(b * 80 + (achunk >> 2)) * 512 + (achunk & 3) * 8;
  const _Float16* bP[4];
#pragma unroll
  for (int j = 0; j < 4; ++j) {
    int c = wave * 256 + j * 64 + lane;
    bP[j] = Bt + (size_t)(c >> 2) * 512 + (c & 3) * 8;
  }
  f32x4 acc[5][4] = {};
  for (int k0 = 0; k0 < 512; k0 += 32) {
    if (wave < 5) GLD16(aP + k0, As + wave * 512);
#pragma unroll
    for (int j = 0; j < 4; ++j)
      GLD16(bP[j] + k0, Bs + (wave * 256 + j * 64) * 8);
    __syncthreads();
    half8 af[5], bfv;
#pragma unroll
    for (int i = 0; i < 5; ++i)
      af[i] = *(const half8*)(As + (i * 16 + lr) * 32 + lk * 8);
#pragma unroll
    for (int j = 0; j < 4; ++j) {
      bfv = *(const half8*)(Bs + (wave * 64 + j * 16 + lr) * 32 + lk * 8);
#pragma unroll
      for (int i = 0; i < 5; ++i)
        acc[i][j] = __builtin_amdgcn_mfma_f32_16x16x32_f16(af[i], bfv, acc[i][j], 0, 0, 0);
    }
    __syncthreads();
  }
  if (wave < 4) {
#pragma unroll
    for (int i = 0; i < 5; ++i)
#pragma unroll
      for (int j = 0; j < 4; ++j)
#pragma unroll
        for (int rg = 0; rg < 4; ++rg) {
          int row = i * 16 + lk * 4 + rg;
          int col = wave * 64 + j * 16 + lr;
          s_x[row * PX + col] = (_Float16)(acc[i][j][rg] + bl2[col]);
        }
  } else if (lk == 3) {
#pragma unroll
    for (int j = 0; j < 4; ++j) {
      int colx = (wave - 4) * 64 + j * 16 + lr;
      s_xr[colx] = (_Float16)(acc[4][j][3] + br2[colx]);
    }
  }
  __syncthreads();
  if (tid < 160) {
    int r = tid >> 1, hf = tid & 1;
    const half2v* xa = (const half2v*)(s_x + r * PX + hf * 128);
    const half2v* xr = (const half2v*)(s_xr + hf * 128);
    const half2v* at = (const half2v*)(s_att + hf * 128);
    float lg = 0.f;
    const half2v c02 = {(_Float16)0.2f, (_Float16)0.2f};
#pragma unroll
    for (int q = 0; q < 64; ++q) {
      half2v e = xa[q] + xr[q];
      half2v l = __builtin_elementwise_max(e, e * c02);
      lg = dot2f(l, at[q], lg);
    }
    lg += __shfl_xor(lg, 1, 64);
    if (hf == 0) s_red[r] = lg;
  }
  __syncthreads();
  if (wave == 7) {
    float v0 = s_red[lane];
    float v1 = (lane < 16) ? s_red[64 + lane] : -3e38f;
    float m = fmaxf(v0, v1);
    for (int d = 32; d; d >>= 1) m = fmaxf(m, __shfl_xor(m, d, 64));
    float e0 = __expf(v0 - m);
    float e1 = (lane < 16) ? __expf(v1 - m) : 0.f;
    float sum = e0 + e1;
    for (int d = 32; d; d >>= 1) sum += __shfl_xor(sum, d, 64);
    float inv = 1.f / sum;
    s_red[lane] = e0 * inv;
    if (lane < 16) s_red[64 + lane] = e1 * inv;
  }
  __syncthreads();
  float v = 0.f;
  if (tid < 256) {
    float a = 0.f;
#pragma unroll
    for (int r = 0; r < 80; ++r) a += s_red[r] * (float)s_x[r * PX + tid];
    v = a + bias2[tid];
    float p = v;
    for (int d = 32; d; d >>= 1) p += __shfl_down(p, d, 64);
    if (lane == 0) s_sum[wave] = p;
    float q = v * v;
    for (int d = 32; d; d >>= 1) q += __shfl_down(q, d, 64);
    if (lane == 0) s_sq[wave] = q;
  }
  __syncthreads();
  if (tid < 256) {
    float mu = (s_sum[0] + s_sum[1] + s_sum[2] + s_sum[3]) * (1.f / 256.f);
    float ex2 = (s_sq[0] + s_sq[1] + s_sq[2] + s_sq[3]) * (1.f / 256.f);
    float var = ex2 - mu * mu;
    float r = rsqrtf(var + 1e-5f);
    out[b * 256 + tid] = (v - mu) * r * ln_g[tid] + ln_b[tid];
  }
}

extern "C" void kernel_launch(void* const* d_in, const int* in_sizes, int n_in,
                              void* d_out, int out_size, void* d_ws, size_t ws_size,
                              hipStream_t stream) {
  const float* x      = (const float*)d_in[0];
  const float* rel    = (const float*)d_in[1];
  const float* w1     = (const float*)d_in[2];
  const float* b1     = (const float*)d_in[3];
  const float* w2     = (const float*)d_in[4];
  const float* b2     = (const float*)d_in[5];
  const float* Wl1    = (const float*)d_in[6];
  const float* bl1    = (const float*)d_in[7];
  const float* Wr1    = (const float*)d_in[8];
  const float* br1    = (const float*)d_in[9];
  const float* att1   = (const float*)d_in[10];
  const float* bias1  = (const float*)d_in[11];
  const float* Wl2    = (const float*)d_in[12];
  const float* bl2    = (const float*)d_in[13];
  const float* Wr2    = (const float*)d_in[14];
  const float* br2    = (const float*)d_in[15];
  const float* att2   = (const float*)d_in[16];
  const float* bias2  = (const float*)d_in[17];
  const float* ln_g   = (const float*)d_in[18];
  const float* ln_b   = (const float*)d_in[19];
  float* out = (float*)d_out;

  char* p = (char*)d_ws;
  _Float16* h0     = (_Float16*)p; p += (size_t)NN * 768 * 2;
  _Float16* h1     = (_Float16*)p; p += (size_t)NN * 512 * 2;
  _Float16* Wt1    = (_Float16*)p; p += (size_t)1024 * 768 * 2;
  _Float16* Wt2cat = (_Float16*)p; p += (size_t)512 * 512 * 2;
  _Float16* att_h  = (_Float16*)p; p += 1024;
  float* biasc     = (float*)p; p += 1024 * 4;

  prep_all<<<NN + 1025, 256, 0, stream>>>(x, rel, w1, b1, w2, b2, Wl1, Wr1, Wl2, Wr2,
                                          bl1, br1, att1, h0, Wt1, Wt2cat, biasc, att_h);

  gemm1gat1<<<1024, 512, 0, stream>>>(h0, Wt1, biasc, att_h, bias1, h1);

  gemm2gat2<<<BB, 512, 0, stream>>>(h1, Wt2cat, bl2, br2, att2, bias2, ln_g, ln_b, out);
}